// Round 1
// baseline (1128.139 us; speedup 1.0000x reference)
//
#include <hip/hip_runtime.h>
#include <math.h>

#define N_NODES 100000
#define N_EDGES 3200000
#define KH 48            // K*H
#define NH 16            // H
#define BN_EPS 1e-5f

// ---------------- degree + histogram ----------------
__global__ __launch_bounds__(256) void deg_hist_kernel(
    const int* __restrict__ col, const float* __restrict__ ea,
    float* __restrict__ deg, int* __restrict__ cnt) {
  int e = blockIdx.x * blockDim.x + threadIdx.x;
  if (e < N_EDGES) {
    int c = col[e];
    atomicAdd(&deg[c], ea[e]);
    atomicAdd(&cnt[c], 1);
  }
}

__global__ __launch_bounds__(256) void dinv_kernel(
    const float* __restrict__ deg, float* __restrict__ dinv) {
  int n = blockIdx.x * blockDim.x + threadIdx.x;
  if (n < N_NODES) {
    float d = deg[n];
    dinv[n] = d > 0.f ? rsqrtf(fmaxf(d, 1e-12f)) : 0.f;
  }
}

// ---------------- exclusive scan (3-kernel hierarchical) ----------------
__global__ __launch_bounds__(1024) void scan1_kernel(
    const int* __restrict__ cnt, int* __restrict__ offs, int* __restrict__ bsums) {
  __shared__ int sh[1024];
  int g = blockIdx.x * 1024 + threadIdx.x;
  int v = (g < N_NODES) ? cnt[g] : 0;
  sh[threadIdx.x] = v;
  __syncthreads();
  for (int d = 1; d < 1024; d <<= 1) {
    int t = (threadIdx.x >= d) ? sh[threadIdx.x - d] : 0;
    __syncthreads();
    sh[threadIdx.x] += t;
    __syncthreads();
  }
  if (g < N_NODES) offs[g] = sh[threadIdx.x] - v;  // exclusive
  if (threadIdx.x == 1023) bsums[blockIdx.x] = sh[1023];
}

__global__ __launch_bounds__(128) void scan2_kernel(int* __restrict__ bsums, int nb) {
  __shared__ int sh[128];
  int t = threadIdx.x;
  int v = (t < nb) ? bsums[t] : 0;
  sh[t] = v;
  __syncthreads();
  for (int d = 1; d < 128; d <<= 1) {
    int u = (t >= d) ? sh[t - d] : 0;
    __syncthreads();
    sh[t] += u;
    __syncthreads();
  }
  if (t < nb) bsums[t] = sh[t] - v;  // exclusive
}

__global__ __launch_bounds__(256) void scan3_kernel(
    int* __restrict__ offs, const int* __restrict__ bsums, int* __restrict__ cursor) {
  int g = blockIdx.x * blockDim.x + threadIdx.x;
  if (g < N_NODES) {
    int v = offs[g] + bsums[g >> 10];
    offs[g] = v;
    cursor[g] = v;
  } else if (g == N_NODES) {
    offs[N_NODES] = N_EDGES;
  }
}

// ---------------- CSR (by destination) build ----------------
__global__ __launch_bounds__(256) void build_csr_kernel(
    const int* __restrict__ row, const int* __restrict__ col,
    const float* __restrict__ ea, const float* __restrict__ dinv,
    int* __restrict__ cursor, int2* __restrict__ csr) {
  int e = blockIdx.x * blockDim.x + threadIdx.x;
  if (e < N_EDGES) {
    int r = row[e], c = col[e];
    float w = dinv[r] * ea[e] * dinv[c];
    int p = atomicAdd(&cursor[c], 1);
    csr[p] = make_int2(r, __float_as_int(w));
  }
}

// ---------------- conv1 init: tmp0 = x @ w1_init ----------------
__global__ __launch_bounds__(256) void conv1_init_kernel(
    const float* __restrict__ x, const float* __restrict__ w1i, float* __restrict__ out) {
  int t = blockIdx.x * blockDim.x + threadIdx.x;
  int n = t >> 6, lane = t & 63;
  if (n < N_NODES && lane < KH) out[(size_t)n * KH + lane] = x[n] * w1i[lane];
}

// ---------------- conv1 propagate (+root+b+relu [+fused W-transform]) ----------------
// wave per node, lane = channel (k*16+f). If do_t: stores (relu_out @ w1) for next layer.
__global__ __launch_bounds__(256) void conv1_prop_kernel(
    const float* __restrict__ tin, float* __restrict__ tout,
    const int2* __restrict__ csr, const int* __restrict__ offs,
    const float* __restrict__ x,
    const float* __restrict__ w1r, const float* __restrict__ b1,
    const float* __restrict__ w1, int do_t) {
  int lane = threadIdx.x & 63;
  int wid = (blockIdx.x * blockDim.x + threadIdx.x) >> 6;
  int nw = (gridDim.x * blockDim.x) >> 6;
  int c = lane;
  bool act = c < KH;
  float rb = act ? w1r[c] : 0.f;
  float bb = act ? b1[c] : 0.f;
  float wreg[16];
  if (do_t) {
    int k = c >> 4, o = c & 15;
    if (act) {
#pragma unroll
      for (int f = 0; f < 16; ++f) wreg[f] = w1[k * 256 + f * 16 + o];
    } else {
#pragma unroll
      for (int f = 0; f < 16; ++f) wreg[f] = 0.f;
    }
  }
  for (int n = wid; n < N_NODES; n += nw) {
    int nu = __builtin_amdgcn_readfirstlane(n);
    int s = offs[nu], e = offs[nu + 1];
    float acc = 0.f;
    int i = s;
    for (; i + 4 <= e; i += 4) {
      int2 e0 = csr[i], e1 = csr[i + 1], e2 = csr[i + 2], e3 = csr[i + 3];
      float v0 = 0.f, v1 = 0.f, v2 = 0.f, v3 = 0.f;
      if (act) {
        v0 = tin[e0.x * KH + c];
        v1 = tin[e1.x * KH + c];
        v2 = tin[e2.x * KH + c];
        v3 = tin[e3.x * KH + c];
      }
      acc += __int_as_float(e0.y) * v0 + __int_as_float(e1.y) * v1 +
             __int_as_float(e2.y) * v2 + __int_as_float(e3.y) * v3;
    }
    for (; i < e; ++i) {
      int2 ew = csr[i];
      if (act) acc += __int_as_float(ew.y) * tin[ew.x * KH + c];
    }
    acc = fmaxf(acc + x[nu] * rb + bb, 0.f);
    if (do_t) {
      float t = 0.f;
      int base = c & 48;
#pragma unroll
      for (int f = 0; f < 16; ++f) t += __shfl(acc, base + f, 64) * wreg[f];
      acc = t;
    }
    if (act) tout[(size_t)nu * KH + c] = acc;
  }
}

// ---------------- BN stats: h = mean_k(out1), accumulate sum/sumsq ----------------
__global__ __launch_bounds__(256) void bn_stats_kernel(
    const float* __restrict__ out1, float* __restrict__ h, double* __restrict__ stats) {
  __shared__ float ssum[NH], ssq[NH];
  int tid = threadIdx.x;
  if (tid < NH) { ssum[tid] = 0.f; ssq[tid] = 0.f; }
  __syncthreads();
  int n = blockIdx.x * blockDim.x + tid;
  bool valid = n < N_NODES;
  const float* p = out1 + (size_t)(valid ? n : 0) * KH;
  float hv[NH];
#pragma unroll
  for (int f = 0; f < NH; ++f) {
    float v = valid ? (p[f] + p[f + 16] + p[f + 32]) * (1.f / 3.f) : 0.f;
    hv[f] = v;
    if (valid) h[(size_t)n * NH + f] = v;
  }
#pragma unroll
  for (int f = 0; f < NH; ++f) {
    float s = hv[f], q = hv[f] * hv[f];
    for (int o = 32; o; o >>= 1) { s += __shfl_xor(s, o, 64); q += __shfl_xor(q, o, 64); }
    if ((tid & 63) == 0) { atomicAdd(&ssum[f], s); atomicAdd(&ssq[f], q); }
  }
  __syncthreads();
  if (tid < NH) {
    atomicAdd(&stats[tid], (double)ssum[tid]);
    atomicAdd(&stats[NH + tid], (double)ssq[tid]);
  }
}

__global__ __launch_bounds__(64) void bn_final_kernel(
    const double* __restrict__ stats, const float* __restrict__ g,
    const float* __restrict__ b, float* __restrict__ sc, float* __restrict__ sh) {
  int f = threadIdx.x;
  if (f < NH) {
    double mu = stats[f] / (double)N_NODES;
    double var = stats[NH + f] / (double)N_NODES - mu * mu;
    float scale = g[f] * (float)(1.0 / sqrt(var + (double)BN_EPS));
    sc[f] = scale;
    sh[f] = b[f] - (float)mu * scale;
  }
}

// ---------------- conv2 init: BN-apply + relu + init/root dots ----------------
__global__ __launch_bounds__(256) void conv2_init_kernel(
    const float* __restrict__ h, const float* __restrict__ sc, const float* __restrict__ sh,
    const float* __restrict__ w2i, const float* __restrict__ w2r, const float* __restrict__ b2,
    float* __restrict__ P, float* __restrict__ R) {
  int n = blockIdx.x * blockDim.x + threadIdx.x;
  if (n >= N_NODES) return;
  float u[NH];
#pragma unroll
  for (int f = 0; f < NH; ++f) u[f] = fmaxf(h[(size_t)n * NH + f] * sc[f] + sh[f], 0.f);
#pragma unroll
  for (int k = 0; k < 3; ++k) {
    float r = b2[k], o = 0.f;
#pragma unroll
    for (int f = 0; f < NH; ++f) {
      r += u[f] * w2r[k * NH + f];
      o += u[f] * w2i[k * NH + f];
    }
    R[n * 4 + k] = r;
    P[n * 4 + k] = o;
  }
  R[n * 4 + 3] = 0.f;
  P[n * 4 + 3] = 0.f;
}

// ---------------- conv2 propagate (+w2 scale + root; final: mean+sigmoid) ----------------
__global__ __launch_bounds__(256) void conv2_prop_kernel(
    const float* __restrict__ in4, float* __restrict__ out4, float* __restrict__ y,
    const int2* __restrict__ csr, const int* __restrict__ offs,
    const float* __restrict__ R, const float* __restrict__ w2,
    int scale_w2, int final_out) {
  int lane = threadIdx.x & 63;
  int wid = (blockIdx.x * blockDim.x + threadIdx.x) >> 6;
  int nw = (gridDim.x * blockDim.x) >> 6;
  float m0 = 1.f, m1 = 1.f, m2 = 1.f;
  if (scale_w2) { m0 = w2[0]; m1 = w2[1]; m2 = w2[2]; }
  for (int n = wid; n < N_NODES; n += nw) {
    int nu = __builtin_amdgcn_readfirstlane(n);
    int s = offs[nu], e = offs[nu + 1];
    float a0 = 0.f, a1 = 0.f, a2 = 0.f;
    for (int i = s + lane; i < e; i += 64) {
      int2 ew = csr[i];
      float w = __int_as_float(ew.y);
      const float4 v = *(const float4*)(in4 + (size_t)ew.x * 4);
      a0 += w * v.x;
      a1 += w * v.y;
      a2 += w * v.z;
    }
#pragma unroll
    for (int o = 32; o; o >>= 1) {
      a0 += __shfl_xor(a0, o, 64);
      a1 += __shfl_xor(a1, o, 64);
      a2 += __shfl_xor(a2, o, 64);
    }
    if (lane == 0) {
      a0 = a0 * m0 + R[nu * 4 + 0];
      a1 = a1 * m1 + R[nu * 4 + 1];
      a2 = a2 * m2 + R[nu * 4 + 2];
      if (final_out) {
        float sm = (a0 + a1 + a2) * (1.f / 3.f);
        y[nu] = 1.f / (1.f + expf(-sm));
      } else {
        out4[nu * 4 + 0] = a0;
        out4[nu * 4 + 1] = a1;
        out4[nu * 4 + 2] = a2;
        out4[nu * 4 + 3] = 0.f;
      }
    }
  }
}

extern "C" void kernel_launch(void* const* d_in, const int* in_sizes, int n_in,
                              void* d_out, int out_size, void* d_ws, size_t ws_size,
                              hipStream_t stream) {
  const float* x   = (const float*)d_in[0];
  const int*   ei  = (const int*)d_in[1];
  const float* ea  = (const float*)d_in[2];
  // d_in[3] = batch (unused)
  const float* w1i = (const float*)d_in[4];
  const float* w1  = (const float*)d_in[5];
  const float* w1r = (const float*)d_in[6];
  const float* b1  = (const float*)d_in[7];
  const float* bng = (const float*)d_in[8];
  const float* bnb = (const float*)d_in[9];
  const float* w2i = (const float*)d_in[10];
  const float* w2  = (const float*)d_in[11];
  const float* w2r = (const float*)d_in[12];
  const float* b2  = (const float*)d_in[13];
  float* y = (float*)d_out;

  const int* row = ei;
  const int* col = ei + N_EDGES;

  char* ws = (char*)d_ws;
  size_t off = 0;
  auto alloc = [&](size_t bytes) -> char* {
    char* p = ws + off;
    off += (bytes + 255) & ~(size_t)255;
    return p;
  };
  float*  deg    = (float*)alloc((size_t)N_NODES * 4);
  float*  dinv   = (float*)alloc((size_t)N_NODES * 4);
  int*    cnt    = (int*)alloc((size_t)N_NODES * 4);
  int*    offs   = (int*)alloc((size_t)(N_NODES + 1) * 4);
  int*    cursor = (int*)alloc((size_t)N_NODES * 4);
  int*    bsums  = (int*)alloc(256 * 4);
  double* stats  = (double*)alloc(32 * 8);
  float*  bnsc   = (float*)alloc(16 * 4);
  float*  bnsh   = (float*)alloc(16 * 4);
  int2*   csr    = (int2*)alloc((size_t)N_EDGES * 8);
  float*  bufA   = (float*)alloc((size_t)N_NODES * KH * 4 + 256);
  float*  bufB   = (float*)alloc((size_t)N_NODES * KH * 4 + 256);
  float*  hbuf   = (float*)alloc((size_t)N_NODES * NH * 4);
  float*  P2     = (float*)alloc((size_t)N_NODES * 4 * 4);
  float*  Q2     = (float*)alloc((size_t)N_NODES * 4 * 4);
  float*  R2     = (float*)alloc((size_t)N_NODES * 4 * 4);
  (void)ws_size; (void)in_sizes; (void)n_in; (void)out_size;

  hipMemsetAsync(deg, 0, (size_t)N_NODES * 4, stream);
  hipMemsetAsync(cnt, 0, (size_t)N_NODES * 4, stream);
  hipMemsetAsync(stats, 0, 32 * 8, stream);

  deg_hist_kernel<<<(N_EDGES + 255) / 256, 256, 0, stream>>>(col, ea, deg, cnt);
  dinv_kernel<<<(N_NODES + 255) / 256, 256, 0, stream>>>(deg, dinv);

  int nblk = (N_NODES + 1023) / 1024;  // 98
  scan1_kernel<<<nblk, 1024, 0, stream>>>(cnt, offs, bsums);
  scan2_kernel<<<1, 128, 0, stream>>>(bsums, nblk);
  scan3_kernel<<<(N_NODES + 1 + 255) / 256, 256, 0, stream>>>(offs, bsums, cursor);
  build_csr_kernel<<<(N_EDGES + 255) / 256, 256, 0, stream>>>(row, col, ea, dinv, cursor, csr);

  conv1_init_kernel<<<(N_NODES * 64) / 256, 256, 0, stream>>>(x, w1i, bufA);
  conv1_prop_kernel<<<4096, 256, 0, stream>>>(bufA, bufB, csr, offs, x, w1r, b1, w1, 1);
  conv1_prop_kernel<<<4096, 256, 0, stream>>>(bufB, bufA, csr, offs, x, w1r, b1, w1, 1);
  conv1_prop_kernel<<<4096, 256, 0, stream>>>(bufA, bufB, csr, offs, x, w1r, b1, w1, 1);
  conv1_prop_kernel<<<4096, 256, 0, stream>>>(bufB, bufA, csr, offs, x, w1r, b1, w1, 0);

  bn_stats_kernel<<<(N_NODES + 255) / 256, 256, 0, stream>>>(bufA, hbuf, stats);
  bn_final_kernel<<<1, 64, 0, stream>>>(stats, bng, bnb, bnsc, bnsh);
  conv2_init_kernel<<<(N_NODES + 255) / 256, 256, 0, stream>>>(hbuf, bnsc, bnsh, w2i, w2r, b2, P2, R2);

  conv2_prop_kernel<<<2048, 256, 0, stream>>>(P2, Q2, nullptr, csr, offs, R2, w2, 0, 0);
  conv2_prop_kernel<<<2048, 256, 0, stream>>>(Q2, P2, nullptr, csr, offs, R2, w2, 1, 0);
  conv2_prop_kernel<<<2048, 256, 0, stream>>>(P2, Q2, nullptr, csr, offs, R2, w2, 1, 0);
  conv2_prop_kernel<<<2048, 256, 0, stream>>>(Q2, P2, y, csr, offs, R2, w2, 1, 1);
}

// Round 2
// 865.447 us; speedup vs baseline: 1.3035x; 1.3035x over previous
//
#include <hip/hip_runtime.h>
#include <math.h>

#define N_NODES 100000
#define N_EDGES 3200000
#define KH 48            // K*H
#define NH 16            // H
#define BN_EPS 1e-5f
#define FIX_SCALE 16777216.0f   // 2^24 fixed-point for deg accumulation

typedef unsigned long long u64;
typedef unsigned int u32;

__device__ __forceinline__ unsigned short f2bf(float f) {
  u32 b = __float_as_uint(f);
  b += 0x7FFFu + ((b >> 16) & 1u);   // RNE
  return (unsigned short)(b >> 16);
}
__device__ __forceinline__ float bf2f(unsigned short s) {
  return __uint_as_float((u32)s << 16);
}

// ---------------- packed histogram: one u64 atomic per edge ----------------
// packed[c] hi32 = count, lo32 = Q8.24 fixed-point sum of ea. Returned old
// hi32 is this edge's unique local index within its destination segment.
__global__ __launch_bounds__(256) void hist_kernel(
    const int* __restrict__ col, const float* __restrict__ ea,
    u64* __restrict__ packed, int* __restrict__ lidx) {
  int e = blockIdx.x * blockDim.x + threadIdx.x;
  if (e < N_EDGES) {
    int c = col[e];
    u64 add = ((u64)1 << 32) | (u64)(u32)(ea[e] * FIX_SCALE);
    u64 old = atomicAdd(&packed[c], add);
    lidx[e] = (int)(old >> 32);
  }
}

__global__ __launch_bounds__(256) void dinv_kernel(
    const u64* __restrict__ packed, float* __restrict__ dinv) {
  int n = blockIdx.x * blockDim.x + threadIdx.x;
  if (n < N_NODES) {
    float d = (float)(u32)(packed[n] & 0xFFFFFFFFull) * (1.0f / FIX_SCALE);
    dinv[n] = d > 0.f ? rsqrtf(fmaxf(d, 1e-12f)) : 0.f;
  }
}

// ---------------- exclusive scan over hi32 of packed ----------------
__global__ __launch_bounds__(1024) void scan1_kernel(
    const u64* __restrict__ packed, int* __restrict__ offs, int* __restrict__ bsums) {
  __shared__ int sh[1024];
  int g = blockIdx.x * 1024 + threadIdx.x;
  int v = (g < N_NODES) ? (int)(packed[g] >> 32) : 0;
  sh[threadIdx.x] = v;
  __syncthreads();
  for (int d = 1; d < 1024; d <<= 1) {
    int t = (threadIdx.x >= d) ? sh[threadIdx.x - d] : 0;
    __syncthreads();
    sh[threadIdx.x] += t;
    __syncthreads();
  }
  if (g < N_NODES) offs[g] = sh[threadIdx.x] - v;  // exclusive
  if (threadIdx.x == 1023) bsums[blockIdx.x] = sh[1023];
}

__global__ __launch_bounds__(128) void scan2_kernel(int* __restrict__ bsums, int nb) {
  __shared__ int sh[128];
  int t = threadIdx.x;
  int v = (t < nb) ? bsums[t] : 0;
  sh[t] = v;
  __syncthreads();
  for (int d = 1; d < 128; d <<= 1) {
    int u = (t >= d) ? sh[t - d] : 0;
    __syncthreads();
    sh[t] += u;
    __syncthreads();
  }
  if (t < nb) bsums[t] = sh[t] - v;  // exclusive
}

__global__ __launch_bounds__(256) void scan3_kernel(
    int* __restrict__ offs, const int* __restrict__ bsums) {
  int g = blockIdx.x * blockDim.x + threadIdx.x;
  if (g < N_NODES) {
    offs[g] = offs[g] + bsums[g >> 10];
  } else if (g == N_NODES) {
    offs[N_NODES] = N_EDGES;
  }
}

// ---------------- CSR (by destination) build — NO atomics ----------------
__global__ __launch_bounds__(256) void build_csr_kernel(
    const int* __restrict__ row, const int* __restrict__ col,
    const float* __restrict__ ea, const float* __restrict__ dinv,
    const int* __restrict__ offs, const int* __restrict__ lidx,
    int2* __restrict__ csr) {
  int e = blockIdx.x * blockDim.x + threadIdx.x;
  if (e < N_EDGES) {
    int r = row[e], c = col[e];
    float w = dinv[r] * ea[e] * dinv[c];
    csr[offs[c] + lidx[e]] = make_int2(r, __float_as_int(w));
  }
}

// ---------------- conv1 init: tmp0 = x @ w1_init (bf16 out) ----------------
__global__ __launch_bounds__(256) void conv1_init_kernel(
    const float* __restrict__ x, const float* __restrict__ w1i,
    unsigned short* __restrict__ out) {
  int t = blockIdx.x * blockDim.x + threadIdx.x;
  int n = t >> 6, lane = t & 63;
  if (n < N_NODES && lane < KH) out[(size_t)n * KH + lane] = f2bf(x[n] * w1i[lane]);
}

// ---------------- conv1 propagate (+root+b+relu [+fused W-transform]) -------
// wave per node, lane = channel (k*16+f). Features stored bf16 between layers;
// final layer (do_t==0) writes fp32 to toutf.
__global__ __launch_bounds__(256) void conv1_prop_kernel(
    const unsigned short* __restrict__ tin, unsigned short* __restrict__ tout,
    float* __restrict__ toutf,
    const int2* __restrict__ csr, const int* __restrict__ offs,
    const float* __restrict__ x,
    const float* __restrict__ w1r, const float* __restrict__ b1,
    const float* __restrict__ w1, int do_t) {
  int lane = threadIdx.x & 63;
  int wid = (blockIdx.x * blockDim.x + threadIdx.x) >> 6;
  int nw = (gridDim.x * blockDim.x) >> 6;
  int c = lane;
  bool act = c < KH;
  float rb = act ? w1r[c] : 0.f;
  float bb = act ? b1[c] : 0.f;
  float wreg[16];
  if (do_t) {
    int k = c >> 4, o = c & 15;
    if (act) {
#pragma unroll
      for (int f = 0; f < 16; ++f) wreg[f] = w1[k * 256 + f * 16 + o];
    } else {
#pragma unroll
      for (int f = 0; f < 16; ++f) wreg[f] = 0.f;
    }
  }
  for (int n = wid; n < N_NODES; n += nw) {
    int nu = __builtin_amdgcn_readfirstlane(n);
    int s = offs[nu], e = offs[nu + 1];
    float acc = 0.f;
    int i = s;
    for (; i + 4 <= e; i += 4) {
      int2 e0 = csr[i], e1 = csr[i + 1], e2 = csr[i + 2], e3 = csr[i + 3];
      float v0 = 0.f, v1 = 0.f, v2 = 0.f, v3 = 0.f;
      if (act) {
        v0 = bf2f(tin[e0.x * KH + c]);
        v1 = bf2f(tin[e1.x * KH + c]);
        v2 = bf2f(tin[e2.x * KH + c]);
        v3 = bf2f(tin[e3.x * KH + c]);
      }
      acc += __int_as_float(e0.y) * v0 + __int_as_float(e1.y) * v1 +
             __int_as_float(e2.y) * v2 + __int_as_float(e3.y) * v3;
    }
    for (; i < e; ++i) {
      int2 ew = csr[i];
      if (act) acc += __int_as_float(ew.y) * bf2f(tin[ew.x * KH + c]);
    }
    acc = fmaxf(acc + x[nu] * rb + bb, 0.f);
    if (do_t) {
      float t = 0.f;
      int base = c & 48;
#pragma unroll
      for (int f = 0; f < 16; ++f) t += __shfl(acc, base + f, 64) * wreg[f];
      if (act) tout[(size_t)nu * KH + c] = f2bf(t);
    } else {
      if (act) toutf[(size_t)nu * KH + c] = acc;
    }
  }
}

// ---------------- BN stats: h = mean_k(out1), accumulate sum/sumsq ----------
__global__ __launch_bounds__(256) void bn_stats_kernel(
    const float* __restrict__ out1, float* __restrict__ h, double* __restrict__ stats) {
  __shared__ float ssum[NH], ssq[NH];
  int tid = threadIdx.x;
  if (tid < NH) { ssum[tid] = 0.f; ssq[tid] = 0.f; }
  __syncthreads();
  int n = blockIdx.x * blockDim.x + tid;
  bool valid = n < N_NODES;
  const float* p = out1 + (size_t)(valid ? n : 0) * KH;
  float hv[NH];
#pragma unroll
  for (int f = 0; f < NH; ++f) {
    float v = valid ? (p[f] + p[f + 16] + p[f + 32]) * (1.f / 3.f) : 0.f;
    hv[f] = v;
    if (valid) h[(size_t)n * NH + f] = v;
  }
#pragma unroll
  for (int f = 0; f < NH; ++f) {
    float s = hv[f], q = hv[f] * hv[f];
    for (int o = 32; o; o >>= 1) { s += __shfl_xor(s, o, 64); q += __shfl_xor(q, o, 64); }
    if ((tid & 63) == 0) { atomicAdd(&ssum[f], s); atomicAdd(&ssq[f], q); }
  }
  __syncthreads();
  if (tid < NH) {
    atomicAdd(&stats[tid], (double)ssum[tid]);
    atomicAdd(&stats[NH + tid], (double)ssq[tid]);
  }
}

__global__ __launch_bounds__(64) void bn_final_kernel(
    const double* __restrict__ stats, const float* __restrict__ g,
    const float* __restrict__ b, float* __restrict__ sc, float* __restrict__ sh) {
  int f = threadIdx.x;
  if (f < NH) {
    double mu = stats[f] / (double)N_NODES;
    double var = stats[NH + f] / (double)N_NODES - mu * mu;
    float scale = g[f] * (float)(1.0 / sqrt(var + (double)BN_EPS));
    sc[f] = scale;
    sh[f] = b[f] - (float)mu * scale;
  }
}

// ---------------- conv2 init: BN-apply + relu + init/root dots ----------------
__global__ __launch_bounds__(256) void conv2_init_kernel(
    const float* __restrict__ h, const float* __restrict__ sc, const float* __restrict__ sh,
    const float* __restrict__ w2i, const float* __restrict__ w2r, const float* __restrict__ b2,
    float* __restrict__ P, float* __restrict__ R) {
  int n = blockIdx.x * blockDim.x + threadIdx.x;
  if (n >= N_NODES) return;
  float u[NH];
#pragma unroll
  for (int f = 0; f < NH; ++f) u[f] = fmaxf(h[(size_t)n * NH + f] * sc[f] + sh[f], 0.f);
#pragma unroll
  for (int k = 0; k < 3; ++k) {
    float r = b2[k], o = 0.f;
#pragma unroll
    for (int f = 0; f < NH; ++f) {
      r += u[f] * w2r[k * NH + f];
      o += u[f] * w2i[k * NH + f];
    }
    R[n * 4 + k] = r;
    P[n * 4 + k] = o;
  }
  R[n * 4 + 3] = 0.f;
  P[n * 4 + 3] = 0.f;
}

// ---------------- conv2 propagate (+w2 scale + root; final: mean+sigmoid) ----
__global__ __launch_bounds__(256) void conv2_prop_kernel(
    const float* __restrict__ in4, float* __restrict__ out4, float* __restrict__ y,
    const int2* __restrict__ csr, const int* __restrict__ offs,
    const float* __restrict__ R, const float* __restrict__ w2,
    int scale_w2, int final_out) {
  int lane = threadIdx.x & 63;
  int wid = (blockIdx.x * blockDim.x + threadIdx.x) >> 6;
  int nw = (gridDim.x * blockDim.x) >> 6;
  float m0 = 1.f, m1 = 1.f, m2 = 1.f;
  if (scale_w2) { m0 = w2[0]; m1 = w2[1]; m2 = w2[2]; }
  for (int n = wid; n < N_NODES; n += nw) {
    int nu = __builtin_amdgcn_readfirstlane(n);
    int s = offs[nu], e = offs[nu + 1];
    float a0 = 0.f, a1 = 0.f, a2 = 0.f;
    for (int i = s + lane; i < e; i += 64) {
      int2 ew = csr[i];
      float w = __int_as_float(ew.y);
      const float4 v = *(const float4*)(in4 + (size_t)ew.x * 4);
      a0 += w * v.x;
      a1 += w * v.y;
      a2 += w * v.z;
    }
#pragma unroll
    for (int o = 32; o; o >>= 1) {
      a0 += __shfl_xor(a0, o, 64);
      a1 += __shfl_xor(a1, o, 64);
      a2 += __shfl_xor(a2, o, 64);
    }
    if (lane == 0) {
      a0 = a0 * m0 + R[nu * 4 + 0];
      a1 = a1 * m1 + R[nu * 4 + 1];
      a2 = a2 * m2 + R[nu * 4 + 2];
      if (final_out) {
        float sm = (a0 + a1 + a2) * (1.f / 3.f);
        y[nu] = 1.f / (1.f + expf(-sm));
      } else {
        out4[nu * 4 + 0] = a0;
        out4[nu * 4 + 1] = a1;
        out4[nu * 4 + 2] = a2;
        out4[nu * 4 + 3] = 0.f;
      }
    }
  }
}

extern "C" void kernel_launch(void* const* d_in, const int* in_sizes, int n_in,
                              void* d_out, int out_size, void* d_ws, size_t ws_size,
                              hipStream_t stream) {
  const float* x   = (const float*)d_in[0];
  const int*   ei  = (const int*)d_in[1];
  const float* ea  = (const float*)d_in[2];
  // d_in[3] = batch (unused)
  const float* w1i = (const float*)d_in[4];
  const float* w1  = (const float*)d_in[5];
  const float* w1r = (const float*)d_in[6];
  const float* b1  = (const float*)d_in[7];
  const float* bng = (const float*)d_in[8];
  const float* bnb = (const float*)d_in[9];
  const float* w2i = (const float*)d_in[10];
  const float* w2  = (const float*)d_in[11];
  const float* w2r = (const float*)d_in[12];
  const float* b2  = (const float*)d_in[13];
  float* y = (float*)d_out;

  const int* row = ei;
  const int* col = ei + N_EDGES;

  char* ws = (char*)d_ws;
  size_t off = 0;
  auto alloc = [&](size_t bytes) -> char* {
    char* p = ws + off;
    off += (bytes + 255) & ~(size_t)255;
    return p;
  };
  u64*    packed = (u64*)alloc((size_t)N_NODES * 8);
  float*  dinv   = (float*)alloc((size_t)N_NODES * 4);
  int*    offs   = (int*)alloc((size_t)(N_NODES + 1) * 4);
  int*    lidx   = (int*)alloc((size_t)N_EDGES * 4);
  int*    bsums  = (int*)alloc(256 * 4);
  double* stats  = (double*)alloc(32 * 8);
  float*  bnsc   = (float*)alloc(16 * 4);
  float*  bnsh   = (float*)alloc(16 * 4);
  int2*   csr    = (int2*)alloc((size_t)N_EDGES * 8);
  unsigned short* bufA = (unsigned short*)alloc((size_t)N_NODES * KH * 2 + 256);
  unsigned short* bufB = (unsigned short*)alloc((size_t)N_NODES * KH * 2 + 256);
  float*  bufF   = (float*)alloc((size_t)N_NODES * KH * 4 + 256);
  float*  hbuf   = (float*)alloc((size_t)N_NODES * NH * 4);
  float*  P2     = (float*)alloc((size_t)N_NODES * 4 * 4);
  float*  Q2     = (float*)alloc((size_t)N_NODES * 4 * 4);
  float*  R2     = (float*)alloc((size_t)N_NODES * 4 * 4);
  (void)ws_size; (void)in_sizes; (void)n_in; (void)out_size;

  hipMemsetAsync(packed, 0, (size_t)N_NODES * 8, stream);
  hipMemsetAsync(stats, 0, 32 * 8, stream);

  hist_kernel<<<(N_EDGES + 255) / 256, 256, 0, stream>>>(col, ea, packed, lidx);
  dinv_kernel<<<(N_NODES + 255) / 256, 256, 0, stream>>>(packed, dinv);

  int nblk = (N_NODES + 1023) / 1024;  // 98
  scan1_kernel<<<nblk, 1024, 0, stream>>>(packed, offs, bsums);
  scan2_kernel<<<1, 128, 0, stream>>>(bsums, nblk);
  scan3_kernel<<<(N_NODES + 1 + 255) / 256, 256, 0, stream>>>(offs, bsums);
  build_csr_kernel<<<(N_EDGES + 255) / 256, 256, 0, stream>>>(row, col, ea, dinv, offs, lidx, csr);

  conv1_init_kernel<<<(N_NODES * 64) / 256, 256, 0, stream>>>(x, w1i, bufA);
  conv1_prop_kernel<<<4096, 256, 0, stream>>>(bufA, bufB, nullptr, csr, offs, x, w1r, b1, w1, 1);
  conv1_prop_kernel<<<4096, 256, 0, stream>>>(bufB, bufA, nullptr, csr, offs, x, w1r, b1, w1, 1);
  conv1_prop_kernel<<<4096, 256, 0, stream>>>(bufA, bufB, nullptr, csr, offs, x, w1r, b1, w1, 1);
  conv1_prop_kernel<<<4096, 256, 0, stream>>>(bufB, nullptr, bufF, csr, offs, x, w1r, b1, w1, 0);

  bn_stats_kernel<<<(N_NODES + 255) / 256, 256, 0, stream>>>(bufF, hbuf, stats);
  bn_final_kernel<<<1, 64, 0, stream>>>(stats, bng, bnb, bnsc, bnsh);
  conv2_init_kernel<<<(N_NODES + 255) / 256, 256, 0, stream>>>(hbuf, bnsc, bnsh, w2i, w2r, b2, P2, R2);

  conv2_prop_kernel<<<2048, 256, 0, stream>>>(P2, Q2, nullptr, csr, offs, R2, w2, 0, 0);
  conv2_prop_kernel<<<2048, 256, 0, stream>>>(Q2, P2, nullptr, csr, offs, R2, w2, 1, 0);
  conv2_prop_kernel<<<2048, 256, 0, stream>>>(P2, Q2, nullptr, csr, offs, R2, w2, 1, 0);
  conv2_prop_kernel<<<2048, 256, 0, stream>>>(Q2, P2, y, csr, offs, R2, w2, 1, 1);
}

// Round 3
// 722.816 us; speedup vs baseline: 1.5608x; 1.1973x over previous
//
#include <hip/hip_runtime.h>
#include <math.h>

#define N_NODES 100000
#define N_EDGES 3200000
#define KH 48            // K*H
#define NH 16            // H
#define BN_EPS 1e-5f
#define NBUCK 196        // ceil(100000/512) buckets of 512 nodes
#define BSHIFT 9
#define BMASK 511
#define EPB 4096         // edges per block in bucket kernels
#define NBLK1 782        // ceil(N_EDGES/EPB)
#define FIX 16777216.0f  // 2^24 fixed point for degree sums

typedef unsigned long long u64;
typedef unsigned int u32;

__device__ __forceinline__ unsigned short f2bf(float f) {
  u32 b = __float_as_uint(f);
  b += 0x7FFFu + ((b >> 16) & 1u);   // RNE
  return (unsigned short)(b >> 16);
}
__device__ __forceinline__ float bf2f(unsigned short s) {
  return __uint_as_float((u32)s << 16);
}

// ---------------- K1: per-block LDS bucket histogram -> global totals -------
__global__ __launch_bounds__(256) void bucket_count_kernel(
    const int* __restrict__ col, u32* __restrict__ btot /* stride 8 */) {
  __shared__ u32 bins[NBUCK];
  for (int t = threadIdx.x; t < NBUCK; t += 256) bins[t] = 0;
  __syncthreads();
  int eb = blockIdx.x * EPB;
#pragma unroll
  for (int it = 0; it < EPB / 256; ++it) {
    int e = eb + it * 256 + threadIdx.x;
    if (e < N_EDGES) atomicAdd(&bins[col[e] >> BSHIFT], 1u);
  }
  __syncthreads();
  for (int t = threadIdx.x; t < NBUCK; t += 256)
    if (bins[t]) atomicAdd(&btot[t * 8], bins[t]);
}

// ---------------- K2: scan bucket totals -> starts, init cursors ------------
__global__ __launch_bounds__(256) void bucket_scan_kernel(
    const u32* __restrict__ btot, u32* __restrict__ bstart, u32* __restrict__ gcur,
    int* __restrict__ offs) {
  __shared__ u32 sh[256];
  int t = threadIdx.x;
  u32 v = (t < NBUCK) ? btot[t * 8] : 0;
  sh[t] = v;
  __syncthreads();
  for (int d = 1; d < 256; d <<= 1) {
    u32 u = (t >= d) ? sh[t - d] : 0;
    __syncthreads();
    sh[t] += u;
    __syncthreads();
  }
  if (t < NBUCK) { u32 s = sh[t] - v; bstart[t] = s; gcur[t * 8] = s; }
  if (t == NBUCK) bstart[NBUCK] = N_EDGES;
  if (t == 0) offs[N_NODES] = N_EDGES;
}

// ---------------- K3: scatter edges into bucket-major order -----------------
__global__ __launch_bounds__(256) void bucket_scatter_kernel(
    const int* __restrict__ row, const int* __restrict__ col,
    const float* __restrict__ ea, u32* __restrict__ gcur,
    int2* __restrict__ bucketed) {
  __shared__ u32 bins[NBUCK];
  __shared__ u32 base[NBUCK];
  __shared__ unsigned short rnk[EPB];
  for (int t = threadIdx.x; t < NBUCK; t += 256) bins[t] = 0;
  __syncthreads();
  int eb = blockIdx.x * EPB;
#pragma unroll
  for (int it = 0; it < EPB / 256; ++it) {
    int i = it * 256 + threadIdx.x;
    int e = eb + i;
    if (e < N_EDGES) rnk[i] = (unsigned short)atomicAdd(&bins[col[e] >> BSHIFT], 1u);
  }
  __syncthreads();
  for (int t = threadIdx.x; t < NBUCK; t += 256) {
    u32 c = bins[t];
    if (c) base[t] = atomicAdd(&gcur[t * 8], c);
  }
  __syncthreads();
#pragma unroll
  for (int it = 0; it < EPB / 256; ++it) {
    int i = it * 256 + threadIdx.x;
    int e = eb + i;
    if (e < N_EDGES) {
      int c = col[e];
      int bkt = c >> BSHIFT, cl = c & BMASK;
      u32 pos = base[bkt] + (u32)rnk[i];
      bucketed[pos] = make_int2((cl << 17) | row[e], __float_as_int(ea[e]));
    }
  }
}

// ---------------- P2a: per-bucket node counts -> offs, dinv -----------------
__global__ __launch_bounds__(1024) void node_offs_kernel(
    const int2* __restrict__ bucketed, const u32* __restrict__ bstart,
    int* __restrict__ offs, float* __restrict__ dinv) {
  __shared__ u32 cnt[512];
  __shared__ u32 degf[512];
  int t = threadIdx.x;
  if (t < 512) { cnt[t] = 0; degf[t] = 0; }
  __syncthreads();
  int b = blockIdx.x;
  u32 s = bstart[b], e = bstart[b + 1];
  for (u32 i = s + t; i < e; i += 1024) {
    int2 v = bucketed[i];
    int cl = (v.x >> 17) & BMASK;
    atomicAdd(&cnt[cl], 1u);
    atomicAdd(&degf[cl], (u32)(__int_as_float(v.y) * FIX));
  }
  __syncthreads();
  u32 v0 = (t < 512) ? cnt[t] : 0;
  for (int d = 1; d < 512; d <<= 1) {
    u32 u = (t < 512 && t >= d) ? cnt[t - d] : 0;
    __syncthreads();
    if (t < 512) cnt[t] += u;
    __syncthreads();
  }
  int n = b * 512 + t;
  if (t < 512 && n < N_NODES) {
    offs[n] = (int)(s + cnt[t] - v0);  // exclusive
    float dg = (float)degf[t] * (1.0f / FIX);
    dinv[n] = dg > 0.f ? rsqrtf(fmaxf(dg, 1e-12f)) : 0.f;
  }
}

// ---------------- P2b: final CSR placement with weights ---------------------
__global__ __launch_bounds__(1024) void csr_fill_kernel(
    const int2* __restrict__ bucketed, const u32* __restrict__ bstart,
    const int* __restrict__ offs, const float* __restrict__ dinv,
    int2* __restrict__ csr) {
  __shared__ u32 cur[512];
  __shared__ float dl[512];
  int t = threadIdx.x;
  int b = blockIdx.x;
  int n = b * 512 + t;
  if (t < 512) {
    cur[t] = (n < N_NODES) ? (u32)offs[n] : 0;
    dl[t] = (n < N_NODES) ? dinv[n] : 0.f;
  }
  __syncthreads();
  u32 s = bstart[b], e = bstart[b + 1];
  for (u32 i = s + t; i < e; i += 1024) {
    int2 v = bucketed[i];
    int cl = (v.x >> 17) & BMASK;
    int r = v.x & 0x1FFFF;
    float w = dinv[r] * __int_as_float(v.y) * dl[cl];
    u32 pos = atomicAdd(&cur[cl], 1u);
    csr[pos] = make_int2(r, __float_as_int(w));
  }
}

// ---------------- conv1 init: tmp0 = x @ w1_init (bf16 out) ----------------
__global__ __launch_bounds__(256) void conv1_init_kernel(
    const float* __restrict__ x, const float* __restrict__ w1i,
    unsigned short* __restrict__ out) {
  int t = blockIdx.x * blockDim.x + threadIdx.x;
  int n = t >> 6, lane = t & 63;
  if (n < N_NODES && lane < KH) out[(size_t)n * KH + lane] = f2bf(x[n] * w1i[lane]);
}

// ---------------- conv1 propagate (+root+b+relu [+fused W-transform]) -------
// wave per node, lane = channel (k*16+f). do_t: store (relu_out @ w1) bf16.
// !do_t (last layer): fuse mean over K, write hbuf [N,16] fp32.
__global__ __launch_bounds__(256) void conv1_prop_kernel(
    const unsigned short* __restrict__ tin, unsigned short* __restrict__ tout,
    float* __restrict__ hbuf,
    const int2* __restrict__ csr, const int* __restrict__ offs,
    const float* __restrict__ x,
    const float* __restrict__ w1r, const float* __restrict__ b1,
    const float* __restrict__ w1, int do_t) {
  int lane = threadIdx.x & 63;
  int wid = (blockIdx.x * blockDim.x + threadIdx.x) >> 6;
  int nw = (gridDim.x * blockDim.x) >> 6;
  int c = lane;
  bool act = c < KH;
  float rb = act ? w1r[c] : 0.f;
  float bb = act ? b1[c] : 0.f;
  float wreg[16];
  if (do_t) {
    int k = c >> 4, o = c & 15;
    if (act) {
#pragma unroll
      for (int f = 0; f < 16; ++f) wreg[f] = w1[k * 256 + f * 16 + o];
    } else {
#pragma unroll
      for (int f = 0; f < 16; ++f) wreg[f] = 0.f;
    }
  }
  for (int n = wid; n < N_NODES; n += nw) {
    int nu = __builtin_amdgcn_readfirstlane(n);
    int s = offs[nu], e = offs[nu + 1];
    float acc = 0.f;
    int i = s;
    for (; i + 4 <= e; i += 4) {
      int2 e0 = csr[i], e1 = csr[i + 1], e2 = csr[i + 2], e3 = csr[i + 3];
      float v0 = 0.f, v1 = 0.f, v2 = 0.f, v3 = 0.f;
      if (act) {
        v0 = bf2f(tin[e0.x * KH + c]);
        v1 = bf2f(tin[e1.x * KH + c]);
        v2 = bf2f(tin[e2.x * KH + c]);
        v3 = bf2f(tin[e3.x * KH + c]);
      }
      acc += __int_as_float(e0.y) * v0 + __int_as_float(e1.y) * v1 +
             __int_as_float(e2.y) * v2 + __int_as_float(e3.y) * v3;
    }
    for (; i < e; ++i) {
      int2 ew = csr[i];
      if (act) acc += __int_as_float(ew.y) * bf2f(tin[ew.x * KH + c]);
    }
    acc = fmaxf(acc + x[nu] * rb + bb, 0.f);
    if (do_t) {
      float t = 0.f;
      int base = c & 48;
#pragma unroll
      for (int f = 0; f < 16; ++f) t += __shfl(acc, base + f, 64) * wreg[f];
      if (act) tout[(size_t)nu * KH + c] = f2bf(t);
    } else {
      float m1v = __shfl(acc, lane + 16, 64);
      float m2v = __shfl(acc, lane + 32, 64);
      if (lane < NH) hbuf[(size_t)nu * NH + lane] = (acc + m1v + m2v) * (1.f / 3.f);
    }
  }
}

// ---------------- BN stats over hbuf [N,16] ---------------------------------
__global__ __launch_bounds__(256) void bn_stats_kernel(
    const float* __restrict__ h, double* __restrict__ stats) {
  __shared__ float ssum[NH], ssq[NH];
  int tid = threadIdx.x;
  if (tid < NH) { ssum[tid] = 0.f; ssq[tid] = 0.f; }
  __syncthreads();
  int n = blockIdx.x * blockDim.x + tid;
  bool valid = n < N_NODES;
  const float4* p = (const float4*)(h + (size_t)(valid ? n : 0) * NH);
  float hv[NH];
#pragma unroll
  for (int q = 0; q < 4; ++q) {
    float4 v = valid ? p[q] : make_float4(0.f, 0.f, 0.f, 0.f);
    hv[q * 4 + 0] = v.x; hv[q * 4 + 1] = v.y; hv[q * 4 + 2] = v.z; hv[q * 4 + 3] = v.w;
  }
#pragma unroll
  for (int f = 0; f < NH; ++f) {
    float s = hv[f], q = hv[f] * hv[f];
    for (int o = 32; o; o >>= 1) { s += __shfl_xor(s, o, 64); q += __shfl_xor(q, o, 64); }
    if ((tid & 63) == 0) { atomicAdd(&ssum[f], s); atomicAdd(&ssq[f], q); }
  }
  __syncthreads();
  if (tid < NH) {
    atomicAdd(&stats[tid], (double)ssum[tid]);
    atomicAdd(&stats[NH + tid], (double)ssq[tid]);
  }
}

__global__ __launch_bounds__(64) void bn_final_kernel(
    const double* __restrict__ stats, const float* __restrict__ g,
    const float* __restrict__ b, float* __restrict__ sc, float* __restrict__ sh) {
  int f = threadIdx.x;
  if (f < NH) {
    double mu = stats[f] / (double)N_NODES;
    double var = stats[NH + f] / (double)N_NODES - mu * mu;
    float scale = g[f] * (float)(1.0 / sqrt(var + (double)BN_EPS));
    sc[f] = scale;
    sh[f] = b[f] - (float)mu * scale;
  }
}

// ---------------- conv2 init: BN-apply + relu + init/root dots --------------
__global__ __launch_bounds__(256) void conv2_init_kernel(
    const float* __restrict__ h, const float* __restrict__ sc, const float* __restrict__ sh,
    const float* __restrict__ w2i, const float* __restrict__ w2r, const float* __restrict__ b2,
    float* __restrict__ P, float* __restrict__ R) {
  int n = blockIdx.x * blockDim.x + threadIdx.x;
  if (n >= N_NODES) return;
  float u[NH];
#pragma unroll
  for (int f = 0; f < NH; ++f) u[f] = fmaxf(h[(size_t)n * NH + f] * sc[f] + sh[f], 0.f);
#pragma unroll
  for (int k = 0; k < 3; ++k) {
    float r = b2[k], o = 0.f;
#pragma unroll
    for (int f = 0; f < NH; ++f) {
      r += u[f] * w2r[k * NH + f];
      o += u[f] * w2i[k * NH + f];
    }
    R[n * 4 + k] = r;
    P[n * 4 + k] = o;
  }
  R[n * 4 + 3] = 0.f;
  P[n * 4 + 3] = 0.f;
}

// ---------------- conv2 propagate: 2 nodes/wave (32-lane groups) ------------
__global__ __launch_bounds__(256) void conv2_prop_kernel(
    const float* __restrict__ in4, float* __restrict__ out4, float* __restrict__ y,
    const int2* __restrict__ csr, const int* __restrict__ offs,
    const float* __restrict__ R, const float* __restrict__ w2,
    int scale_w2, int final_out) {
  int lane = threadIdx.x & 63;
  int half = lane >> 5, sub = lane & 31;
  int gid = (((blockIdx.x * blockDim.x + threadIdx.x) >> 6) << 1) + half;
  int ng = ((gridDim.x * blockDim.x) >> 6) << 1;
  float m0 = 1.f, m1 = 1.f, m2 = 1.f;
  if (scale_w2) { m0 = w2[0]; m1 = w2[1]; m2 = w2[2]; }
  for (int n = gid; n < N_NODES; n += ng) {
    int s = offs[n], e = offs[n + 1];
    float a0 = 0.f, a1 = 0.f, a2 = 0.f;
    for (int i = s + sub; i < e; i += 32) {
      int2 ew = csr[i];
      float w = __int_as_float(ew.y);
      const float4 v = *(const float4*)(in4 + (size_t)ew.x * 4);
      a0 += w * v.x;
      a1 += w * v.y;
      a2 += w * v.z;
    }
#pragma unroll
    for (int o = 16; o; o >>= 1) {
      a0 += __shfl_xor(a0, o, 64);
      a1 += __shfl_xor(a1, o, 64);
      a2 += __shfl_xor(a2, o, 64);
    }
    if (sub == 0) {
      a0 = a0 * m0 + R[n * 4 + 0];
      a1 = a1 * m1 + R[n * 4 + 1];
      a2 = a2 * m2 + R[n * 4 + 2];
      if (final_out) {
        float sm = (a0 + a1 + a2) * (1.f / 3.f);
        y[n] = 1.f / (1.f + expf(-sm));
      } else {
        out4[n * 4 + 0] = a0;
        out4[n * 4 + 1] = a1;
        out4[n * 4 + 2] = a2;
        out4[n * 4 + 3] = 0.f;
      }
    }
  }
}

extern "C" void kernel_launch(void* const* d_in, const int* in_sizes, int n_in,
                              void* d_out, int out_size, void* d_ws, size_t ws_size,
                              hipStream_t stream) {
  const float* x   = (const float*)d_in[0];
  const int*   ei  = (const int*)d_in[1];
  const float* ea  = (const float*)d_in[2];
  // d_in[3] = batch (unused)
  const float* w1i = (const float*)d_in[4];
  const float* w1  = (const float*)d_in[5];
  const float* w1r = (const float*)d_in[6];
  const float* b1  = (const float*)d_in[7];
  const float* bng = (const float*)d_in[8];
  const float* bnb = (const float*)d_in[9];
  const float* w2i = (const float*)d_in[10];
  const float* w2  = (const float*)d_in[11];
  const float* w2r = (const float*)d_in[12];
  const float* b2  = (const float*)d_in[13];
  float* y = (float*)d_out;

  const int* row = ei;
  const int* col = ei + N_EDGES;

  char* ws = (char*)d_ws;
  size_t off = 0;
  auto alloc = [&](size_t bytes) -> char* {
    char* p = ws + off;
    off += (bytes + 255) & ~(size_t)255;
    return p;
  };
  u32*    btot   = (u32*)alloc((size_t)NBUCK * 8 * 4);
  u32*    gcur   = (u32*)alloc((size_t)NBUCK * 8 * 4);
  u32*    bstart = (u32*)alloc((size_t)(NBUCK + 1) * 4);
  int*    offs   = (int*)alloc((size_t)(N_NODES + 1) * 4);
  float*  dinv   = (float*)alloc((size_t)N_NODES * 4);
  double* stats  = (double*)alloc(32 * 8);
  float*  bnsc   = (float*)alloc(16 * 4);
  float*  bnsh   = (float*)alloc(16 * 4);
  int2*   bucketed = (int2*)alloc((size_t)N_EDGES * 8);
  int2*   csr    = (int2*)alloc((size_t)N_EDGES * 8);
  unsigned short* bufA = (unsigned short*)alloc((size_t)N_NODES * KH * 2 + 256);
  unsigned short* bufB = (unsigned short*)alloc((size_t)N_NODES * KH * 2 + 256);
  float*  hbuf   = (float*)alloc((size_t)N_NODES * NH * 4);
  float*  P2     = (float*)alloc((size_t)N_NODES * 4 * 4);
  float*  Q2     = (float*)alloc((size_t)N_NODES * 4 * 4);
  float*  R2     = (float*)alloc((size_t)N_NODES * 4 * 4);
  (void)ws_size; (void)in_sizes; (void)n_in; (void)out_size;

  hipMemsetAsync(btot, 0, (size_t)NBUCK * 8 * 4, stream);
  hipMemsetAsync(stats, 0, 32 * 8, stream);

  bucket_count_kernel<<<NBLK1, 256, 0, stream>>>(col, btot);
  bucket_scan_kernel<<<1, 256, 0, stream>>>(btot, bstart, gcur, offs);
  bucket_scatter_kernel<<<NBLK1, 256, 0, stream>>>(row, col, ea, gcur, bucketed);
  node_offs_kernel<<<NBUCK, 1024, 0, stream>>>(bucketed, bstart, offs, dinv);
  csr_fill_kernel<<<NBUCK, 1024, 0, stream>>>(bucketed, bstart, offs, dinv, csr);

  conv1_init_kernel<<<(N_NODES * 64) / 256, 256, 0, stream>>>(x, w1i, bufA);
  conv1_prop_kernel<<<4096, 256, 0, stream>>>(bufA, bufB, nullptr, csr, offs, x, w1r, b1, w1, 1);
  conv1_prop_kernel<<<4096, 256, 0, stream>>>(bufB, bufA, nullptr, csr, offs, x, w1r, b1, w1, 1);
  conv1_prop_kernel<<<4096, 256, 0, stream>>>(bufA, bufB, nullptr, csr, offs, x, w1r, b1, w1, 1);
  conv1_prop_kernel<<<4096, 256, 0, stream>>>(bufB, nullptr, hbuf, csr, offs, x, w1r, b1, w1, 0);

  bn_stats_kernel<<<(N_NODES + 255) / 256, 256, 0, stream>>>(hbuf, stats);
  bn_final_kernel<<<1, 64, 0, stream>>>(stats, bng, bnb, bnsc, bnsh);
  conv2_init_kernel<<<(N_NODES + 255) / 256, 256, 0, stream>>>(hbuf, bnsc, bnsh, w2i, w2r, b2, P2, R2);

  conv2_prop_kernel<<<2048, 256, 0, stream>>>(P2, Q2, nullptr, csr, offs, R2, w2, 0, 0);
  conv2_prop_kernel<<<2048, 256, 0, stream>>>(Q2, P2, nullptr, csr, offs, R2, w2, 1, 0);
  conv2_prop_kernel<<<2048, 256, 0, stream>>>(P2, Q2, nullptr, csr, offs, R2, w2, 1, 0);
  conv2_prop_kernel<<<2048, 256, 0, stream>>>(Q2, P2, y, csr, offs, R2, w2, 1, 1);
}